// Round 17
// baseline (219.236 us; speedup 1.0000x reference)
//
#include <hip/hip_runtime.h>
#include <stdint.h>

#define NROW 8192
#define MCOL 8192
#define DH 64

// scale * log2(e): softmax computed as exp2(s * SC2) / sum
#define SC2 0.18033688011112042f

typedef __attribute__((ext_vector_type(8))) short short8;   // 8 bf16 (4 VGPRs)
typedef __attribute__((ext_vector_type(4))) short bf16x4;   // 4 bf16 (2 VGPRs)
typedef __attribute__((ext_vector_type(4))) float f32x4;
typedef __attribute__((ext_vector_type(4))) int   i32x4;

__device__ __forceinline__ short8 ldb8(const uint16_t* p) {
    return *reinterpret_cast<const short8*>(p);
}

__device__ __forceinline__ uint16_t f2bf(float f) {
    uint32_t u = __builtin_bit_cast(uint32_t, f);
    uint32_t r = (u + 0x7fffu + ((u >> 16) & 1u)) >> 16;
    return (uint16_t)r;
}

// async global->LDS, 16 bytes per lane; LDS dest = wave-uniform base + lane*16
__device__ __forceinline__ void gload_lds16(const void* g, void* l) {
    __builtin_amdgcn_global_load_lds(
        (const __attribute__((address_space(1))) void*)g,
        (__attribute__((address_space(3))) void*)l, 16, 0, 0);
}

// ---------------- k_prep: Q,K -> bf16 ; V -> bf16 transposed Vt[d][c] ---------
__global__ __launch_bounds__(256) void k_prep(const float* __restrict__ Q,
                                              const float* __restrict__ K,
                                              const float* __restrict__ V,
                                              uint16_t* __restrict__ Qb,
                                              uint16_t* __restrict__ Kb,
                                              uint16_t* __restrict__ Vt) {
    int b = blockIdx.x, t = threadIdx.x;
    if (b < 128) {
        // transpose V rows [c0, c0+64) into Vt[dv][c]
        __shared__ float tile[64][65];
        int c0 = b * 64;
#pragma unroll
        for (int it = 0; it < 4; ++it) {
            int r = it * 16 + (t >> 4);
            int col = (t & 15) * 4;
            f32x4 v = *reinterpret_cast<const f32x4*>(V + (size_t)(c0 + r) * DH + col);
            tile[r][col + 0] = v[0]; tile[r][col + 1] = v[1];
            tile[r][col + 2] = v[2]; tile[r][col + 3] = v[3];
        }
        __syncthreads();
        int dv = t >> 2, cs = (t & 3) * 16;
        short8 o0, o1;
#pragma unroll
        for (int i = 0; i < 8; ++i) o0[i] = (short)f2bf(tile[cs + i][dv]);
#pragma unroll
        for (int i = 0; i < 8; ++i) o1[i] = (short)f2bf(tile[cs + 8 + i][dv]);
        *reinterpret_cast<short8*>(Vt + (size_t)dv * MCOL + c0 + cs) = o0;
        *reinterpret_cast<short8*>(Vt + (size_t)dv * MCOL + c0 + cs + 8) = o1;
    } else {
        const float* src; uint16_t* dst; int base;
        if (b < 640) { base = (b - 128) * 1024 + t * 4; src = Q; dst = Qb; }
        else         { base = (b - 640) * 1024 + t * 4; src = K; dst = Kb; }
        f32x4 v = *reinterpret_cast<const f32x4*>(src + base);
        uint64_t pk = (uint64_t)f2bf(v[0]) | ((uint64_t)f2bf(v[1]) << 16) |
                      ((uint64_t)f2bf(v[2]) << 32) | ((uint64_t)f2bf(v[3]) << 48);
        *reinterpret_cast<uint64_t*>(dst + base) = pk;
    }
}

// ---------------- k_pass1: row sums of masked exp + mask bit-packing ----------
// Barrier-free async mask staging: each wave double-buffers ITS OWN 16 rows of
// the mask chunk in LDS via global_load_lds (coalesced 16B/lane), and reads
// them back consumption-ordered (granule-swizzled, conflict-free b128). Only a
// per-wave counted vmcnt orders stage->read; no __syncthreads anywhere.
// LDS granule swizzle: lm[r] granule gi holds mask granule gi^(r&7).
__global__ __launch_bounds__(256, 5) void k_pass1(const uint16_t* __restrict__ Qb,
                                               const uint16_t* __restrict__ Kb,
                                               const int* __restrict__ mask,
                                               unsigned long long* __restrict__ pm2,
                                               float* __restrict__ lpart,
                                               int nstrip, int write_pm) {
    __shared__ int lm[2][64][64];   // 32 KB: dbuf 64x64 int mask chunk
    int b = blockIdx.x + gridDim.x * blockIdx.y;
    int rb, s;
    if (nstrip == 16) {    // XCD-aware: xcd = b&7 owns strips {2*xcd, 2*xcd+1}
        int idx = b >> 3;
        s = (b & 7) * 2 + (idx >> 7);
        rb = idx & 127;
    } else { rb = blockIdx.x; s = blockIdx.y; }
    int t = threadIdx.x, lane = t & 63, w = t >> 6;
    int rw0 = rb * 64;
    int rw = rw0 + w * 16;
    int li = lane & 15, g = lane >> 4;

    const uint16_t* qbase = Qb + (size_t)(rw + li) * DH + g * 8;
    short8 qa0 = ldb8(qbase), qa1 = ldb8(qbase + 32);

    float rs = 0.f;
    int steps = 128 / nstrip;
    int c00 = s * steps * 64;

    // prologue: stage chunk 0 (wave w stages its own rows w*16..w*16+15)
#pragma unroll
    for (int i = 0; i < 4; ++i) {
        int r = w * 16 + i * 4 + (lane >> 4);
        int sg = (lane & 15) ^ (r & 7);
        gload_lds16(mask + (size_t)(rw0 + r) * MCOL + c00 + sg * 4,
                    &lm[0][w * 16 + i * 4][0]);
    }
    asm volatile("s_waitcnt vmcnt(0)" ::: "memory");
    __builtin_amdgcn_sched_barrier(0);

    int cur = 0;
    for (int ccl = 0; ccl < steps; ++ccl) {
        int cc = s * steps + ccl;
        int c0 = cc * 64;
        // issue next chunk's staging into the other buffer (per-wave private)
        if (ccl + 1 < steps) {
            int c0n = c0 + 64;
#pragma unroll
            for (int i = 0; i < 4; ++i) {
                int r = w * 16 + i * 4 + (lane >> 4);
                int sg = (lane & 15) ^ (r & 7);
                gload_lds16(mask + (size_t)(rw0 + r) * MCOL + c0n + sg * 4,
                            &lm[cur ^ 1][w * 16 + i * 4][0]);
            }
            __builtin_amdgcn_sched_barrier(0);
            // allow the 4 fresh staging issues; everything older (this chunk's
            // staging, prior pm2 store) must be complete before the LDS reads
            asm volatile("s_waitcnt vmcnt(4)" ::: "memory");
        } else {
            asm volatile("s_waitcnt vmcnt(0)" ::: "memory");
        }
        __builtin_amdgcn_sched_barrier(0);

        // consumption-ordered mask reads from LDS (conflict-free b128):
        // lane (li,g) -> row w*16+li, mask granule ct*4+g at gi^(li&7)
        i32x4 mv[4];
#pragma unroll
        for (int ct = 0; ct < 4; ++ct) {
            int gi = (ct * 4 + g) ^ (li & 7);
            mv[ct] = *reinterpret_cast<const i32x4*>(&lm[cur][w * 16 + li][gi * 4]);
        }
        // pm2 side path: row li's 64-bit word, OR across the 4 g-lanes
        if (write_pm) {
            unsigned long long wloc = 0ull;
#pragma unroll
            for (int ct = 0; ct < 4; ++ct) {
#pragma unroll
                for (int j = 0; j < 4; ++j)
                    wloc |= (unsigned long long)(mv[ct][j] != 0 ? 1u : 0u)
                            << (ct * 16 + g * 4 + j);
            }
            wloc |= __shfl_xor(wloc, 16);
            wloc |= __shfl_xor(wloc, 32);
            if (lane < 16)
                pm2[(size_t)cc * NROW + rw + lane] = wloc;
        }

#pragma unroll
        for (int ct = 0; ct < 4; ++ct) {
            const uint16_t* kbase = Kb + (size_t)(c0 + ct * 16 + li) * DH + g * 8;
            short8 kb0 = ldb8(kbase), kb1 = ldb8(kbase + 32);
            f32x4 acc = {0.f, 0.f, 0.f, 0.f};
            acc = __builtin_amdgcn_mfma_f32_16x16x32_bf16(kb0, qa0, acc, 0, 0, 0);
            acc = __builtin_amdgcn_mfma_f32_16x16x32_bf16(kb1, qa1, acc, 0, 0, 0);
#pragma unroll
            for (int j = 0; j < 4; ++j) {
                if (mv[ct][j] == 0)
                    rs += __builtin_amdgcn_exp2f(acc[j] * SC2);
            }
        }
        cur ^= 1;
    }
    // reduce across the 4 g-lanes holding the same q-row
    rs += __shfl_xor(rs, 16);
    rs += __shfl_xor(rs, 32);
    if (lane < 16)
        lpart[(size_t)s * NROW + rw + lane] = rs;
}

// swizzled LDS chunk layout: element (row, u16col) lives at
//   u16 index row*64 + (u16col ^ ((row&7)<<3))          [byte ^= (row&7)<<4]
// async stage via global_load_lds: wave-uniform LDS base + lane*16B, source
// address pre-swizzled per lane (m173 pattern). Waves 0-7 stage K, 8-15 V.

// ---------------- k_pass2: probs + context partials ---------------------------
// Swapped QK^T + counted-vmcnt barrier: prob stores stay in flight ACROSS the
// chunk barrier (vmcnt(4) = staging load + pm2 done, 4 NT stores outstanding).
__global__ __launch_bounds__(1024, 8) void k_pass2(const uint16_t* __restrict__ Qb,
                                               const uint16_t* __restrict__ Kb,
                                               const uint16_t* __restrict__ Vt,
                                               const unsigned long long* __restrict__ pm2,
                                               const float* __restrict__ lpart,
                                               float* __restrict__ out_prob,
                                               float* __restrict__ ctx_out,
                                               int nstrip) {
    __shared__ uint16_t ks[2][4096];    // K-chunk double buffer, XOR-swizzled
    __shared__ uint16_t vs[2][4096];    // Vt-chunk double buffer, XOR-swizzled
    __shared__ uint16_t pt[16][1024];   // per-wave 16x64 bf16 P, XOR-swizzled
    int b = blockIdx.x + gridDim.x * blockIdx.y;
    int rb, s;
    if (nstrip == 16) {    // XCD-aware: xcd = b&7 owns strips {2*xcd, 2*xcd+1}
        int idx = b >> 3;
        s = (b & 7) * 2 + (idx >> 5);
        rb = idx & 31;
    } else { rb = blockIdx.x; s = blockIdx.y; }
    int t = threadIdx.x, lane = t & 63, w = t >> 6;
    int rw = rb * 256 + w * 16;
    int li = lane & 15, g = lane >> 4;

    int srow = (t >> 3) & 63;
    int scol = ((t & 7) << 3) ^ ((srow & 7) << 3);
    int whalf = (t < 512) ? w : (w - 8);

    // 1/l for this lane's q-row (sum strip partials)
    float lsum = 0.f;
    for (int s2 = 0; s2 < nstrip; ++s2)
        lsum += lpart[(size_t)s2 * NROW + rw + li];
    float rinv = 1.0f / lsum;

    const uint16_t* qbase = Qb + (size_t)(rw + li) * DH + g * 8;
    short8 qa0 = ldb8(qbase), qa1 = ldb8(qbase + 32);

    f32x4 ctx[4];
#pragma unroll
    for (int dt = 0; dt < 4; ++dt) ctx[dt] = (f32x4){0.f, 0.f, 0.f, 0.f};

    int steps = 128 / nstrip;
    int cbase0 = s * steps * 64;
    // prologue: async-stage chunk 0 into buffer 0
    {
        const uint16_t* gp = (t < 512)
            ? (Kb + (size_t)(cbase0 + srow) * DH + scol)
            : (Vt + (size_t)srow * MCOL + cbase0 + scol);
        uint16_t* lp = (t < 512) ? &ks[0][whalf * 512] : &vs[0][whalf * 512];
        gload_lds16(gp, lp);
    }
    __syncthreads();   // chunk 0 staged (full drain: nothing else outstanding)

    int cur = 0;
    for (int ccl = 0; ccl < steps; ++ccl) {
        int cc = s * steps + ccl;
        int c0 = cc * 64;
        // issue next chunk's async staging FIRST (oldest vmem op this chunk)
        if (ccl + 1 < steps) {
            int c0n = c0 + 64;
            const uint16_t* gp = (t < 512)
                ? (Kb + (size_t)(c0n + srow) * DH + scol)
                : (Vt + (size_t)srow * MCOL + c0n + scol);
            uint16_t* lp = (t < 512) ? &ks[cur ^ 1][whalf * 512]
                                     : &vs[cur ^ 1][whalf * 512];
            gload_lds16(gp, lp);
        }
        __builtin_amdgcn_sched_barrier(0);   // pin: staging issue stays first
        unsigned long long w64 = pm2[(size_t)cc * NROW + rw + li];

#pragma unroll
        for (int ct = 0; ct < 4; ++ct) {
            int r = ct * 16 + li;
            short8 kb0 = ldb8(&ks[cur][r * 64 + ((g * 8) ^ ((li & 7) << 3))]);
            short8 kb1 = ldb8(&ks[cur][r * 64 + ((32 + g * 8) ^ ((li & 7) << 3))]);
            f32x4 acc = {0.f, 0.f, 0.f, 0.f};
            acc = __builtin_amdgcn_mfma_f32_16x16x32_bf16(kb0, qa0, acc, 0, 0, 0);
            acc = __builtin_amdgcn_mfma_f32_16x16x32_bf16(kb1, qa1, acc, 0, 0, 0);
            uint32_t nib = (uint32_t)(w64 >> (ct * 16 + g * 4)) & 15u;
            f32x4 o;
#pragma unroll
            for (int j = 0; j < 4; ++j)
                o[j] = ((nib >> j) & 1u) ? 0.0f
                     : __builtin_amdgcn_exp2f(acc[j] * SC2) * rinv;
            // direct NT prob store: 4 consecutive cols of row rw+li
            __builtin_nontemporal_store(
                o, reinterpret_cast<f32x4*>(
                       &out_prob[(size_t)(rw + li) * MCOL + c0 + ct * 16 + g * 4]));
            // packed bf16 write into P-tile (one b64 per lane per ct)
            bf16x4 pk;
            pk[0] = (short)f2bf(o[0]); pk[1] = (short)f2bf(o[1]);
            pk[2] = (short)f2bf(o[2]); pk[3] = (short)f2bf(o[3]);
            int e = (li << 6) + ((ct * 16 + g * 4) ^ ((li & 7) << 3));
            *reinterpret_cast<bf16x4*>(&pt[w][e]) = pk;
        }
        // PV: context += P(16x64) * V(64x64), both operands from LDS
#pragma unroll
        for (int kc = 0; kc < 2; ++kc) {
            int eidx = ((li << 6) + kc * 32 + (g << 3)) ^ ((li & 7) << 3);
            short8 pa = *reinterpret_cast<const short8*>(&pt[w][eidx]);
#pragma unroll
            for (int dt = 0; dt < 4; ++dt) {
                int d = dt * 16 + li;
                short8 bv = ldb8(&vs[cur][d * 64 + ((kc * 32 + g * 8) ^ ((li & 7) << 3))]);
                ctx[dt] = __builtin_amdgcn_mfma_f32_16x16x32_bf16(pa, bv, ctx[dt], 0, 0, 0);
            }
        }
        // counted-vmcnt barrier: drain LDS reads (buffer-reuse safety) and the
        // staging load + pm2 (oldest 2 vmem), leave the 4 NT stores in flight.
        if (ccl + 1 < steps) {
            asm volatile("s_waitcnt lgkmcnt(0)" ::: "memory");
            asm volatile("s_waitcnt vmcnt(4)" ::: "memory");
            __builtin_amdgcn_sched_barrier(0);
            __builtin_amdgcn_s_barrier();
            __builtin_amdgcn_sched_barrier(0);
        }
        cur ^= 1;
    }
    // write context partial for this strip (stream-once -> NT)
    float* cbase = ctx_out + (size_t)s * NROW * DH;
#pragma unroll
    for (int dt = 0; dt < 4; ++dt)
#pragma unroll
        for (int j = 0; j < 4; ++j)
            __builtin_nontemporal_store(
                ctx[dt][j], &cbase[(size_t)(rw + g * 4 + j) * DH + dt * 16 + li]);
}

// ---------------- k_red: reduce context strip partials ------------------------
__global__ __launch_bounds__(256) void k_red(const float* __restrict__ cpart,
                                             float* __restrict__ out, int nstrip) {
    int i = blockIdx.x * 256 + threadIdx.x;   // 524288 total
    float a = 0.f;
    for (int s = 0; s < nstrip; ++s)
        a += __builtin_nontemporal_load(&cpart[(size_t)s * (NROW * DH) + i]);
    out[i] = a;
}

extern "C" void kernel_launch(void* const* d_in, const int* in_sizes, int n_in,
                              void* d_out, int out_size, void* d_ws, size_t ws_size,
                              hipStream_t stream) {
    const float* Q = (const float*)d_in[0];
    const float* K = (const float*)d_in[1];
    const float* V = (const float*)d_in[2];
    const int* mask = (const int*)d_in[3];

    float* out_ctx = (float*)d_out;
    float* out_prob = out_ctx + (size_t)NROW * DH;
    char* ws = (char*)d_ws;

    uint16_t* Qb = (uint16_t*)(ws);
    uint16_t* Kb = (uint16_t*)(ws + (1u << 20));
    uint16_t* Vt = (uint16_t*)(ws + (2u << 20));
    float* lpart = (float*)(ws + (3u << 20));          // up to 16 strips x 32 KB
    size_t off_pm = (3u << 20) + (1u << 19);           // 3.5 MB
    unsigned long long* pm2 = (unsigned long long*)(ws + off_pm);
    size_t pm_bytes = (size_t)128 * NROW * 8;          // 8 MB
    size_t off_ctx = off_pm + pm_bytes;                // 11.5 MB
    size_t ctx_strip = (size_t)NROW * DH * 4;          // 2 MB per strip

    int nstrip; float* ctx_out;
    if (ws_size >= off_ctx + 16 * ctx_strip)      { nstrip = 16; ctx_out = (float*)(ws + off_ctx); }
    else if (ws_size >= off_ctx + 8 * ctx_strip)  { nstrip = 8;  ctx_out = (float*)(ws + off_ctx); }
    else                                          { nstrip = 1;  ctx_out = out_ctx; }

    k_prep<<<dim3(1152), dim3(256), 0, stream>>>(Q, K, V, Qb, Kb, Vt);
    k_pass1<<<dim3(128, nstrip), dim3(256), 0, stream>>>(Qb, Kb, mask, pm2, lpart,
                                                         nstrip, 1);
    k_pass2<<<dim3(32, nstrip), dim3(1024), 0, stream>>>(
        Qb, Kb, Vt, pm2, lpart, out_prob, ctx_out, nstrip);
    if (nstrip > 1)
        k_red<<<dim3(2048), dim3(256), 0, stream>>>(ctx_out, out_ctx, nstrip);
}

// Round 18
// 215.258 us; speedup vs baseline: 1.0185x; 1.0185x over previous
//
#include <hip/hip_runtime.h>
#include <stdint.h>

#define NROW 8192
#define MCOL 8192
#define DH 64

// scale * log2(e): softmax computed as exp2(s * SC2) / sum
#define SC2 0.18033688011112042f

typedef __attribute__((ext_vector_type(8))) short short8;   // 8 bf16 (4 VGPRs)
typedef __attribute__((ext_vector_type(4))) short bf16x4;   // 4 bf16 (2 VGPRs)
typedef __attribute__((ext_vector_type(4))) float f32x4;
typedef __attribute__((ext_vector_type(4))) int   i32x4;

__device__ __forceinline__ short8 ldb8(const uint16_t* p) {
    return *reinterpret_cast<const short8*>(p);
}

__device__ __forceinline__ uint16_t f2bf(float f) {
    uint32_t u = __builtin_bit_cast(uint32_t, f);
    uint32_t r = (u + 0x7fffu + ((u >> 16) & 1u)) >> 16;
    return (uint16_t)r;
}

// async global->LDS, 16 bytes per lane; LDS dest = wave-uniform base + lane*16
__device__ __forceinline__ void gload_lds16(const void* g, void* l) {
    __builtin_amdgcn_global_load_lds(
        (const __attribute__((address_space(1))) void*)g,
        (__attribute__((address_space(3))) void*)l, 16, 0, 0);
}

// ---------------- k_prep: Q,K -> bf16 ; V -> bf16 transposed Vt[d][c] ---------
__global__ __launch_bounds__(256) void k_prep(const float* __restrict__ Q,
                                              const float* __restrict__ K,
                                              const float* __restrict__ V,
                                              uint16_t* __restrict__ Qb,
                                              uint16_t* __restrict__ Kb,
                                              uint16_t* __restrict__ Vt) {
    int b = blockIdx.x, t = threadIdx.x;
    if (b < 128) {
        // transpose V rows [c0, c0+64) into Vt[dv][c]
        __shared__ float tile[64][65];
        int c0 = b * 64;
#pragma unroll
        for (int it = 0; it < 4; ++it) {
            int r = it * 16 + (t >> 4);
            int col = (t & 15) * 4;
            f32x4 v = *reinterpret_cast<const f32x4*>(V + (size_t)(c0 + r) * DH + col);
            tile[r][col + 0] = v[0]; tile[r][col + 1] = v[1];
            tile[r][col + 2] = v[2]; tile[r][col + 3] = v[3];
        }
        __syncthreads();
        int dv = t >> 2, cs = (t & 3) * 16;
        short8 o0, o1;
#pragma unroll
        for (int i = 0; i < 8; ++i) o0[i] = (short)f2bf(tile[cs + i][dv]);
#pragma unroll
        for (int i = 0; i < 8; ++i) o1[i] = (short)f2bf(tile[cs + 8 + i][dv]);
        *reinterpret_cast<short8*>(Vt + (size_t)dv * MCOL + c0 + cs) = o0;
        *reinterpret_cast<short8*>(Vt + (size_t)dv * MCOL + c0 + cs + 8) = o1;
    } else {
        const float* src; uint16_t* dst; int base;
        if (b < 640) { base = (b - 128) * 1024 + t * 4; src = Q; dst = Qb; }
        else         { base = (b - 640) * 1024 + t * 4; src = K; dst = Kb; }
        f32x4 v = *reinterpret_cast<const f32x4*>(src + base);
        uint64_t pk = (uint64_t)f2bf(v[0]) | ((uint64_t)f2bf(v[1]) << 16) |
                      ((uint64_t)f2bf(v[2]) << 32) | ((uint64_t)f2bf(v[3]) << 48);
        *reinterpret_cast<uint64_t*>(dst + base) = pk;
    }
}

// ---------------- k_pass1: row sums of masked exp + mask bit-packing ----------
// R16 structure (coalesced 256B/row mask loads, u32-halves OR-reduce, LDS-free
// redistribute). A/B vs R16: mask loads are REGULAR (NT hint removed) so the
// stream benefits from L2 line aggregation.
__global__ __launch_bounds__(256, 8) void k_pass1(const uint16_t* __restrict__ Qb,
                                               const uint16_t* __restrict__ Kb,
                                               const int* __restrict__ mask,
                                               unsigned long long* __restrict__ pm2,
                                               float* __restrict__ lpart,
                                               int nstrip, int write_pm) {
    int b = blockIdx.x + gridDim.x * blockIdx.y;
    int rb, s;
    if (nstrip == 16) {    // XCD-aware: xcd = b&7 owns strips {2*xcd, 2*xcd+1}
        int idx = b >> 3;
        s = (b & 7) * 2 + (idx >> 7);
        rb = idx & 127;
    } else { rb = blockIdx.x; s = blockIdx.y; }
    int t = threadIdx.x, lane = t & 63, w = t >> 6;
    int rw = rb * 64 + w * 16;
    int li = lane & 15, g = lane >> 4;

    const uint16_t* qbase = Qb + (size_t)(rw + li) * DH + g * 8;
    short8 qa0 = ldb8(qbase), qa1 = ldb8(qbase + 32);

    float rs = 0.f;
    int steps = 128 / nstrip;

    for (int ccl = 0; ccl < steps; ++ccl) {
        int cc = s * steps + ccl;
        int c0 = cc * 64;
        // mask: 4x int4 per lane covers 16 rows x 64 cols (256B/row segments);
        // OR-reduce in u32 halves -> every lane of group g holds row (it*4+g)
        unsigned long long rm0, rm1, rm2, rm3;
#pragma unroll
        for (int it = 0; it < 4; ++it) {
            const i32x4* mp = reinterpret_cast<const i32x4*>(
                &mask[(size_t)(rw + it * 4 + g) * MCOL + c0 + li * 4]);
            i32x4 mv = *mp;   // regular load (A/B: NT removed)
            uint32_t nib = (mv[0] != 0 ? 1u : 0u) | (mv[1] != 0 ? 2u : 0u) |
                           (mv[2] != 0 ? 4u : 0u) | (mv[3] != 0 ? 8u : 0u);
            uint32_t h = nib << ((li & 7) * 4);
            h |= __shfl_xor(h, 1);
            h |= __shfl_xor(h, 2);
            h |= __shfl_xor(h, 4);
            uint32_t o = __shfl_xor(h, 8);   // other half-word of the row
            unsigned long long rm = (li & 8)
                ? (((unsigned long long)h << 32) | o)
                : (((unsigned long long)o << 32) | h);
            if (it == 0) rm0 = rm; else if (it == 1) rm1 = rm;
            else if (it == 2) rm2 = rm; else rm3 = rm;
        }
        // redistribute: lane (li,g) wants row li, held by group (li&3) at
        // slot (li>>2). Source lane ((li&3)<<4)|li provides rm[li>>2].
        unsigned long long v = (li & 8) ? ((li & 4) ? rm3 : rm2)
                                        : ((li & 4) ? rm1 : rm0);
        unsigned long long w64 = __shfl(v, ((li & 3) << 4) | li);
        if (write_pm && lane < 16)
            pm2[(size_t)cc * NROW + rw + lane] = w64;

#pragma unroll
        for (int ct = 0; ct < 4; ++ct) {
            const uint16_t* kbase = Kb + (size_t)(c0 + ct * 16 + li) * DH + g * 8;
            short8 kb0 = ldb8(kbase), kb1 = ldb8(kbase + 32);
            f32x4 acc = {0.f, 0.f, 0.f, 0.f};
            acc = __builtin_amdgcn_mfma_f32_16x16x32_bf16(kb0, qa0, acc, 0, 0, 0);
            acc = __builtin_amdgcn_mfma_f32_16x16x32_bf16(kb1, qa1, acc, 0, 0, 0);
            uint32_t nib = (uint32_t)(w64 >> (ct * 16 + g * 4)) & 15u;
#pragma unroll
            for (int j = 0; j < 4; ++j) {
                if (!((nib >> j) & 1u))
                    rs += __builtin_amdgcn_exp2f(acc[j] * SC2);
            }
        }
    }
    // reduce across the 4 g-lanes holding the same q-row
    rs += __shfl_xor(rs, 16);
    rs += __shfl_xor(rs, 32);
    if (lane < 16)
        lpart[(size_t)s * NROW + rw + lane] = rs;
}

// swizzled LDS chunk layout: element (row, u16col) lives at
//   u16 index row*64 + (u16col ^ ((row&7)<<3))          [byte ^= (row&7)<<4]
// async stage via global_load_lds: wave-uniform LDS base + lane*16B, source
// address pre-swizzled per lane (m173 pattern). Waves 0-7 stage K, 8-15 V.

// ---------------- k_pass2: probs + context partials ---------------------------
// Swapped QK^T + counted-vmcnt barrier: prob stores stay in flight ACROSS the
// chunk barrier (vmcnt(4) = staging load + pm2 done, 4 NT stores outstanding).
__global__ __launch_bounds__(1024, 8) void k_pass2(const uint16_t* __restrict__ Qb,
                                               const uint16_t* __restrict__ Kb,
                                               const uint16_t* __restrict__ Vt,
                                               const unsigned long long* __restrict__ pm2,
                                               const float* __restrict__ lpart,
                                               float* __restrict__ out_prob,
                                               float* __restrict__ ctx_out,
                                               int nstrip) {
    __shared__ uint16_t ks[2][4096];    // K-chunk double buffer, XOR-swizzled
    __shared__ uint16_t vs[2][4096];    // Vt-chunk double buffer, XOR-swizzled
    __shared__ uint16_t pt[16][1024];   // per-wave 16x64 bf16 P, XOR-swizzled
    int b = blockIdx.x + gridDim.x * blockIdx.y;
    int rb, s;
    if (nstrip == 16) {    // XCD-aware: xcd = b&7 owns strips {2*xcd, 2*xcd+1}
        int idx = b >> 3;
        s = (b & 7) * 2 + (idx >> 5);
        rb = idx & 31;
    } else { rb = blockIdx.x; s = blockIdx.y; }
    int t = threadIdx.x, lane = t & 63, w = t >> 6;
    int rw = rb * 256 + w * 16;
    int li = lane & 15, g = lane >> 4;

    int srow = (t >> 3) & 63;
    int scol = ((t & 7) << 3) ^ ((srow & 7) << 3);
    int whalf = (t < 512) ? w : (w - 8);

    // 1/l for this lane's q-row (sum strip partials)
    float lsum = 0.f;
    for (int s2 = 0; s2 < nstrip; ++s2)
        lsum += lpart[(size_t)s2 * NROW + rw + li];
    float rinv = 1.0f / lsum;

    const uint16_t* qbase = Qb + (size_t)(rw + li) * DH + g * 8;
    short8 qa0 = ldb8(qbase), qa1 = ldb8(qbase + 32);

    f32x4 ctx[4];
#pragma unroll
    for (int dt = 0; dt < 4; ++dt) ctx[dt] = (f32x4){0.f, 0.f, 0.f, 0.f};

    int steps = 128 / nstrip;
    int cbase0 = s * steps * 64;
    // prologue: async-stage chunk 0 into buffer 0
    {
        const uint16_t* gp = (t < 512)
            ? (Kb + (size_t)(cbase0 + srow) * DH + scol)
            : (Vt + (size_t)srow * MCOL + cbase0 + scol);
        uint16_t* lp = (t < 512) ? &ks[0][whalf * 512] : &vs[0][whalf * 512];
        gload_lds16(gp, lp);
    }
    __syncthreads();   // chunk 0 staged (full drain: nothing else outstanding)

    int cur = 0;
    for (int ccl = 0; ccl < steps; ++ccl) {
        int cc = s * steps + ccl;
        int c0 = cc * 64;
        // issue next chunk's async staging FIRST (oldest vmem op this chunk)
        if (ccl + 1 < steps) {
            int c0n = c0 + 64;
            const uint16_t* gp = (t < 512)
                ? (Kb + (size_t)(c0n + srow) * DH + scol)
                : (Vt + (size_t)srow * MCOL + c0n + scol);
            uint16_t* lp = (t < 512) ? &ks[cur ^ 1][whalf * 512]
                                     : &vs[cur ^ 1][whalf * 512];
            gload_lds16(gp, lp);
        }
        __builtin_amdgcn_sched_barrier(0);   // pin: staging issue stays first
        unsigned long long w64 = pm2[(size_t)cc * NROW + rw + li];

#pragma unroll
        for (int ct = 0; ct < 4; ++ct) {
            int r = ct * 16 + li;
            short8 kb0 = ldb8(&ks[cur][r * 64 + ((g * 8) ^ ((li & 7) << 3))]);
            short8 kb1 = ldb8(&ks[cur][r * 64 + ((32 + g * 8) ^ ((li & 7) << 3))]);
            f32x4 acc = {0.f, 0.f, 0.f, 0.f};
            acc = __builtin_amdgcn_mfma_f32_16x16x32_bf16(kb0, qa0, acc, 0, 0, 0);
            acc = __builtin_amdgcn_mfma_f32_16x16x32_bf16(kb1, qa1, acc, 0, 0, 0);
            uint32_t nib = (uint32_t)(w64 >> (ct * 16 + g * 4)) & 15u;
            f32x4 o;
#pragma unroll
            for (int j = 0; j < 4; ++j)
                o[j] = ((nib >> j) & 1u) ? 0.0f
                     : __builtin_amdgcn_exp2f(acc[j] * SC2) * rinv;
            // direct NT prob store: 4 consecutive cols of row rw+li
            __builtin_nontemporal_store(
                o, reinterpret_cast<f32x4*>(
                       &out_prob[(size_t)(rw + li) * MCOL + c0 + ct * 16 + g * 4]));
            // packed bf16 write into P-tile (one b64 per lane per ct)
            bf16x4 pk;
            pk[0] = (short)f2bf(o[0]); pk[1] = (short)f2bf(o[1]);
            pk[2] = (short)f2bf(o[2]); pk[3] = (short)f2bf(o[3]);
            int e = (li << 6) + ((ct * 16 + g * 4) ^ ((li & 7) << 3));
            *reinterpret_cast<bf16x4*>(&pt[w][e]) = pk;
        }
        // PV: context += P(16x64) * V(64x64), both operands from LDS
#pragma unroll
        for (int kc = 0; kc < 2; ++kc) {
            int eidx = ((li << 6) + kc * 32 + (g << 3)) ^ ((li & 7) << 3);
            short8 pa = *reinterpret_cast<const short8*>(&pt[w][eidx]);
#pragma unroll
            for (int dt = 0; dt < 4; ++dt) {
                int d = dt * 16 + li;
                short8 bv = ldb8(&vs[cur][d * 64 + ((kc * 32 + g * 8) ^ ((li & 7) << 3))]);
                ctx[dt] = __builtin_amdgcn_mfma_f32_16x16x32_bf16(pa, bv, ctx[dt], 0, 0, 0);
            }
        }
        // counted-vmcnt barrier: drain LDS reads (buffer-reuse safety) and the
        // staging load + pm2 (oldest 2 vmem), leave the 4 NT stores in flight.
        if (ccl + 1 < steps) {
            asm volatile("s_waitcnt lgkmcnt(0)" ::: "memory");
            asm volatile("s_waitcnt vmcnt(4)" ::: "memory");
            __builtin_amdgcn_sched_barrier(0);
            __builtin_amdgcn_s_barrier();
            __builtin_amdgcn_sched_barrier(0);
        }
        cur ^= 1;
    }
    // write context partial for this strip (stream-once -> NT)
    float* cbase = ctx_out + (size_t)s * NROW * DH;
#pragma unroll
    for (int dt = 0; dt < 4; ++dt)
#pragma unroll
        for (int j = 0; j < 4; ++j)
            __builtin_nontemporal_store(
                ctx[dt][j], &cbase[(size_t)(rw + g * 4 + j) * DH + dt * 16 + li]);
}

// ---------------- k_red: reduce context strip partials ------------------------
__global__ __launch_bounds__(256) void k_red(const float* __restrict__ cpart,
                                             float* __restrict__ out, int nstrip) {
    int i = blockIdx.x * 256 + threadIdx.x;   // 524288 total
    float a = 0.f;
    for (int s = 0; s < nstrip; ++s)
        a += __builtin_nontemporal_load(&cpart[(size_t)s * (NROW * DH) + i]);
    out[i] = a;
}

extern "C" void kernel_launch(void* const* d_in, const int* in_sizes, int n_in,
                              void* d_out, int out_size, void* d_ws, size_t ws_size,
                              hipStream_t stream) {
    const float* Q = (const float*)d_in[0];
    const float* K = (const float*)d_in[1];
    const float* V = (const float*)d_in[2];
    const int* mask = (const int*)d_in[3];

    float* out_ctx = (float*)d_out;
    float* out_prob = out_ctx + (size_t)NROW * DH;
    char* ws = (char*)d_ws;

    uint16_t* Qb = (uint16_t*)(ws);
    uint16_t* Kb = (uint16_t*)(ws + (1u << 20));
    uint16_t* Vt = (uint16_t*)(ws + (2u << 20));
    float* lpart = (float*)(ws + (3u << 20));          // up to 16 strips x 32 KB
    size_t off_pm = (3u << 20) + (1u << 19);           // 3.5 MB
    unsigned long long* pm2 = (unsigned long long*)(ws + off_pm);
    size_t pm_bytes = (size_t)128 * NROW * 8;          // 8 MB
    size_t off_ctx = off_pm + pm_bytes;                // 11.5 MB
    size_t ctx_strip = (size_t)NROW * DH * 4;          // 2 MB per strip

    int nstrip; float* ctx_out;
    if (ws_size >= off_ctx + 16 * ctx_strip)      { nstrip = 16; ctx_out = (float*)(ws + off_ctx); }
    else if (ws_size >= off_ctx + 8 * ctx_strip)  { nstrip = 8;  ctx_out = (float*)(ws + off_ctx); }
    else                                          { nstrip = 1;  ctx_out = out_ctx; }

    k_prep<<<dim3(1152), dim3(256), 0, stream>>>(Q, K, V, Qb, Kb, Vt);
    k_pass1<<<dim3(128, nstrip), dim3(256), 0, stream>>>(Qb, Kb, mask, pm2, lpart,
                                                         nstrip, 1);
    k_pass2<<<dim3(32, nstrip), dim3(1024), 0, stream>>>(
        Qb, Kb, Vt, pm2, lpart, out_prob, ctx_out, nstrip);
    if (nstrip > 1)
        k_red<<<dim3(2048), dim3(256), 0, stream>>>(ctx_out, out_ctx, nstrip);
}